// Round 5
// baseline (785.534 us; speedup 1.0000x reference)
//
#include <hip/hip_runtime.h>

typedef unsigned int uint_t;

#define N_NODES 100000
#define N_EDGES 1600000
#define D 64
#define D2 4096   // D*D
#define D3 12288  // 3*D2

#define NPAD 100352u  // N_NODES rounded up

#define BSHIFT 9          // 512 nodes per bucket
#define BNODES 512
#define NBUCK 196         // ceil(100000/512)
#define CHUNK 8192        // edges per partition workgroup (196 workgroups)
#define CAP   16384       // LDS staging slots in bucket_csr (mean fill 8192)

#define GRU_ROWS 8        // rows per block in gru_matvec

// ---------- workspace layout (4-byte units) ----------
#define OFF_GI1   0u
#define OFF_GI2   (OFF_GI1 + D3)
#define OFF_GH1   (OFF_GI2 + D3)
#define OFF_GH2   (OFF_GH1 + D3)
#define OFF_W1    (OFF_GH2 + D3)          // 49152
#define OFF_W2    (OFF_W1 + D2)           // 53248
#define OFF_DEG   (OFF_W2 + D2)           // 57344   int[NPAD]
#define OFF_NORM  (OFF_DEG + NPAD)        // 157696  float[NPAD]
#define OFF_ROWS  (OFF_NORM + NPAD)       // 258048  int[NPAD] rowstart (node-ordered)
#define OFF_BCNT  (OFF_ROWS + NPAD)       // 358400  int[256]
#define OFF_BBASE (OFF_BCNT + 256u)       // 358656  int[256]
#define OFF_BCUR  (OFF_BBASE + 256u)      // 358912  int[256]
#define OFF_CSR   (OFF_BCUR + 256u)       // 359168  int[N_EDGES]
#define OFF_H     (OFF_CSR + 1600000u)    // 1959168 float[N*D]; PAIRS aliases first 3.2M
#define OFF_AGG1  (OFF_H + 6400000u)      // 8359168 float[N*D]
// total 14,759,168 units ~= 56.3 MiB

__device__ __forceinline__ float dot4(float4 a, float4 b, float acc) {
    acc = fmaf(a.x, b.x, acc);
    acc = fmaf(a.y, b.y, acc);
    acc = fmaf(a.z, b.z, acc);
    acc = fmaf(a.w, b.w, acc);
    return acc;
}

// K1: 4 matvecs in one pass over w_ih,w_hh (fp32).
// R4 post-mortem: 64KB-LDS staging dropped occupancy to 19% and put ds_read
// waits inside the streaming loop -> 1.07 TB/s. New structure: thread-owned
// x fragments in REGISTERS (loaded once per block, 8x less cached re-read than
// per-row), 8 rows per block with a pure-VMEM streaming loop (no LDS, no
// barrier), then ONE LDS reduction phase at the end. Grid 1536 x 256.
__global__ __launch_bounds__(256) void gru_matvec(
    const float* __restrict__ w_ih, const float* __restrict__ w_hh,
    const float* __restrict__ x1, const float* __restrict__ x2,
    const float* __restrict__ h1, const float* __restrict__ h2,
    float* __restrict__ gi1, float* __restrict__ gi2,
    float* __restrict__ gh1, float* __restrict__ gh2)
{
    __shared__ float part[256][GRU_ROWS * 4 + 1];   // +1 pad -> 2-way banks (free)
    const int tid = threadIdx.x;
    const int r0  = blockIdx.x * GRU_ROWS;

    // preload x/h fragments: thread owns float4 slots {tid, tid+256, tid+512, tid+768}
    float4 fx1[4], fx2[4], fh1[4], fh2[4];
    {
        const float4* vx1 = (const float4*)x1;
        const float4* vx2 = (const float4*)x2;
        const float4* vh1 = (const float4*)h1;
        const float4* vh2 = (const float4*)h2;
#pragma unroll
        for (int c = 0; c < 4; ++c) {
            const int idx = tid + c * 256;
            fx1[c] = vx1[idx]; fx2[c] = vx2[idx];
            fh1[c] = vh1[idx]; fh2[c] = vh2[idx];
        }
    }

    float p[GRU_ROWS][4];
#pragma unroll
    for (int r = 0; r < GRU_ROWS; ++r)
#pragma unroll
        for (int o = 0; o < 4; ++o) p[r][o] = 0.f;

#pragma unroll
    for (int r = 0; r < GRU_ROWS; ++r) {
        const float4* wi = (const float4*)(w_ih + (size_t)(r0 + r) * D2);
        const float4* wh = (const float4*)(w_hh + (size_t)(r0 + r) * D2);
        float4 a[4], b[4];
#pragma unroll
        for (int c = 0; c < 4; ++c) {       // 8 independent streaming loads
            a[c] = wi[tid + c * 256];
            b[c] = wh[tid + c * 256];
        }
#pragma unroll
        for (int c = 0; c < 4; ++c) {
            p[r][0] = dot4(a[c], fx1[c], p[r][0]);
            p[r][1] = dot4(a[c], fx2[c], p[r][1]);
            p[r][2] = dot4(b[c], fh1[c], p[r][2]);
            p[r][3] = dot4(b[c], fh2[c], p[r][3]);
        }
    }

    // single reduction phase: stage 32 partials, cross-thread reduce
#pragma unroll
    for (int r = 0; r < GRU_ROWS; ++r)
#pragma unroll
        for (int o = 0; o < 4; ++o)
            part[tid][r * 4 + o] = p[r][o];
    __syncthreads();

    const int wave = tid >> 6, lane = tid & 63;
#pragma unroll
    for (int i = 0; i < 8; ++i) {           // wave handles 8 (row,out) pairs
        const int k = wave * 8 + i;
        float s = part[lane][k] + part[lane + 64][k]
                + part[lane + 128][k] + part[lane + 192][k];
#pragma unroll
        for (int m = 32; m > 0; m >>= 1) s += __shfl_down(s, m, 64);
        if (lane == 0) {
            const int row = r0 + (k >> 2);
            const int o = k & 3;
            float* outp = (o == 0) ? gi1 : (o == 1) ? gi2 : (o == 2) ? gh1 : gh2;
            outp[row] = s;
        }
    }
}

// K2: GRU gates -> evolved weights w1,w2 (fp32, 4096 each)
__global__ __launch_bounds__(256) void gru_gates(
    const float* __restrict__ gi1, const float* __restrict__ gh1,
    const float* __restrict__ gi2, const float* __restrict__ gh2,
    const float* __restrict__ b_ih, const float* __restrict__ b_hh,
    const float* __restrict__ hw1, const float* __restrict__ hw2,
    float* __restrict__ w1, float* __restrict__ w2)
{
    const int j = blockIdx.x * 256 + threadIdx.x;   // 0..4095
    const int layer = blockIdx.y;
    const float* gi = layer ? gi2 : gi1;
    const float* gh = layer ? gh2 : gh1;
    const float* hw = layer ? hw2 : hw1;
    float* wo = layer ? w2 : w1;

    float ir = gi[j]          + b_ih[j];
    float hr = gh[j]          + b_hh[j];
    float iz = gi[j + D2]     + b_ih[j + D2];
    float hz = gh[j + D2]     + b_hh[j + D2];
    float in_ = gi[j + 2*D2]  + b_ih[j + 2*D2];
    float hn = gh[j + 2*D2]   + b_hh[j + 2*D2];

    float r = 1.f / (1.f + expf(-(ir + hr)));
    float z = 1.f / (1.f + expf(-(iz + hz)));
    float n = tanhf(in_ + r * hn);
    wo[j] = (1.f - z) * n + z * hw[j];
}

// K3: fused in-degree + bucket histogram (grid-stride, LDS-pre-aggregated)
__global__ __launch_bounds__(256) void deg_hist_kernel(
    const int* __restrict__ dst, int* __restrict__ deg, int* __restrict__ bcnt)
{
    __shared__ int hist[256];
    const int tid = threadIdx.x;
    hist[tid] = 0;
    __syncthreads();
    const int stride = gridDim.x * 256;
    for (int e = blockIdx.x * 256 + tid; e < N_EDGES; e += stride) {
        const int d = dst[e];
        atomicAdd(&deg[d], 1);
        atomicAdd(&hist[d >> BSHIFT], 1);
    }
    __syncthreads();
    if (hist[tid]) atomicAdd(&bcnt[tid], hist[tid]);
}

// K4: exclusive scan of 256 bucket counts -> bucket base + write cursor
__global__ __launch_bounds__(256) void bucket_scan_kernel(
    const int* __restrict__ bcnt, int* __restrict__ bbase, int* __restrict__ bcur)
{
    __shared__ int tmp[256];
    const int tid = threadIdx.x;
    const int c = bcnt[tid];
    tmp[tid] = c;
    __syncthreads();
    for (int off = 1; off < 256; off <<= 1) {
        int a = tmp[tid];
        int b = (tid >= off) ? tmp[tid - off] : 0;
        __syncthreads();
        tmp[tid] = a + b;
        __syncthreads();
    }
    const int ex = tmp[tid] - c;
    bbase[tid] = ex;
    bcur[tid]  = ex;
}

// K5: norm = clip(deg,1)^-0.5
__global__ __launch_bounds__(256) void norm_kernel(
    const int* __restrict__ deg, float* __restrict__ norm)
{
    const int n = blockIdx.x * 256 + threadIdx.x;
    if (n < N_NODES) norm[n] = 1.0f / sqrtf(fmaxf((float)deg[n], 1.0f));
}

// K6: partition edges into dst-buckets. All global writes are coalesced runs
// (avg ~42 int2 per bucket per chunk) instead of 4B scatters.
__global__ __launch_bounds__(256) void partition_kernel(
    const int* __restrict__ src, const int* __restrict__ dst,
    int* __restrict__ bcur, int2* __restrict__ pairs)
{
    __shared__ int hist[256];
    __shared__ int lbase[256];
    __shared__ int gbase[256];
    __shared__ int lcur[256];
    __shared__ int2 stage[CHUNK];
    const int tid = threadIdx.x;
    const int e0  = blockIdx.x * CHUNK;
    const int cnt = min(CHUNK, N_EDGES - e0);

    hist[tid] = 0; lcur[tid] = 0;
    __syncthreads();
    for (int i = tid; i < cnt; i += 256)
        atomicAdd(&hist[dst[e0 + i] >> BSHIFT], 1);
    __syncthreads();
    // scan hist -> exclusive lbase; reserve global space per bucket
    {
        const int c = hist[tid];
        lbase[tid] = c;
        __syncthreads();
        for (int off = 1; off < 256; off <<= 1) {
            int a = lbase[tid];
            int b = (tid >= off) ? lbase[tid - off] : 0;
            __syncthreads();
            lbase[tid] = a + b;
            __syncthreads();
        }
        const int inc = lbase[tid];       // own slot only
        lbase[tid] = inc - c;
        if (c) gbase[tid] = atomicAdd(&bcur[tid], c);
        __syncthreads();
    }
    // scatter into LDS by bucket
    for (int i = tid; i < cnt; i += 256) {
        const int s = src[e0 + i], d = dst[e0 + i];
        const int b = d >> BSHIFT;
        const int p = lbase[b] + atomicAdd(&lcur[b], 1);
        stage[p] = make_int2(s, d);
    }
    __syncthreads();
    // flush: consecutive i -> consecutive global positions within each bucket run
    for (int i = tid; i < cnt; i += 256) {
        const int2 v = stage[i];
        const int b = v.y >> BSHIFT;
        pairs[gbase[b] + (i - lbase[b])] = v;
    }
}

// K7: per-bucket CSR finalize. One workgroup per bucket: scan local degrees ->
// exact node-ordered rowstart; scatter the bucket's edges INSIDE LDS; flush
// the final CSR region with fully coalesced stores. Zero scattered global writes
// (fallback path only if a bucket exceeds CAP=2x mean — statistically never).
__global__ __launch_bounds__(256) void bucket_csr_kernel(
    const int2* __restrict__ pairs, const int* __restrict__ deg,
    const int* __restrict__ bbase, const int* __restrict__ bcnt,
    int* __restrict__ rowstart, int* __restrict__ csr_src)
{
    __shared__ int lofs[BNODES];
    __shared__ int lcur[BNODES];
    __shared__ int pscan[256];
    __shared__ int stage[CAP];     // 64KB
    const int tid = threadIdx.x;
    const int b   = blockIdx.x;
    const int nodeBase = b << BSHIFT;

    // scan 512 local degrees (2 per thread) -> exclusive offsets
    const int n0 = nodeBase + 2 * tid;
    const int d0 = (n0     < N_NODES) ? deg[n0]     : 0;
    const int d1 = (n0 + 1 < N_NODES) ? deg[n0 + 1] : 0;
    pscan[tid] = d0 + d1;
    __syncthreads();
    for (int off = 1; off < 256; off <<= 1) {
        int a = pscan[tid];
        int x = (tid >= off) ? pscan[tid - off] : 0;
        __syncthreads();
        pscan[tid] = a + x;
        __syncthreads();
    }
    const int ex = pscan[tid] - (d0 + d1);
    lofs[2 * tid]     = ex;
    lofs[2 * tid + 1] = ex + d0;
    lcur[2 * tid]     = 0;
    lcur[2 * tid + 1] = 0;

    const int base = bbase[b];
    if (n0     < N_NODES) rowstart[n0]     = base + ex;
    if (n0 + 1 < N_NODES) rowstart[n0 + 1] = base + ex + d0;
    __syncthreads();

    const int cnt = bcnt[b];
    if (cnt <= CAP) {
        for (int i = tid; i < cnt; i += 256) {
            const int2 v = pairs[base + i];
            const int ln = v.y - nodeBase;
            const int p  = lofs[ln] + atomicAdd(&lcur[ln], 1);
            stage[p] = v.x;
        }
        __syncthreads();
        for (int i = tid; i < cnt; i += 256)
            csr_src[base + i] = stage[i];
    } else {
        for (int i = tid; i < cnt; i += 256) {
            const int2 v = pairs[base + i];
            const int ln = v.y - nodeBase;
            const int p  = atomicAdd(&lcur[ln], 1);
            csr_src[base + lofs[ln] + p] = v.x;
        }
    }
}

// K8/K10: dense transform out[node] = (relu?)(x[node]) @ w, w staged in LDS
template <bool RELU>
__global__ __launch_bounds__(256) void transform_kernel(
    const float* __restrict__ xin, const float* __restrict__ w,
    float* __restrict__ out)
{
    __shared__ float sw[D * D];
    const int tid = threadIdx.x;
#pragma unroll
    for (int i = 0; i < 16; ++i) sw[tid + i * 256] = w[tid + i * 256];
    __syncthreads();

    const int node = blockIdx.x * 256 + tid;
    if (node >= N_NODES) return;

    float x[D];
    const float4* p = (const float4*)(xin + (size_t)node * D);
#pragma unroll
    for (int i = 0; i < 16; ++i) {
        float4 u = p[i];
        x[i * 4 + 0] = u.x; x[i * 4 + 1] = u.y;
        x[i * 4 + 2] = u.z; x[i * 4 + 3] = u.w;
    }
    if (RELU) {
#pragma unroll
        for (int k = 0; k < D; ++k) x[k] = fmaxf(x[k], 0.f);
    }

    float acc[D];
#pragma unroll
    for (int j = 0; j < D; ++j) acc[j] = 0.f;
#pragma unroll
    for (int k = 0; k < D; ++k) {
        float a = x[k];
#pragma unroll
        for (int j = 0; j < D; ++j) acc[j] = fmaf(a, sw[k * D + j], acc[j]);
    }

    float4* po = (float4*)(out + (size_t)node * D);
#pragma unroll
    for (int i = 0; i < 16; ++i)
        po[i] = make_float4(acc[i*4], acc[i*4+1], acc[i*4+2], acc[i*4+3]);
}

// K9/K11: gather aggregation. One wave per node, NO atomics.
// end = rowstart[n] + deg[n]. All __shfl execute with wave-uniform trip counts.
__global__ __launch_bounds__(256) void aggregate_gather(
    const float* __restrict__ h, const int* __restrict__ csr_src,
    const int* __restrict__ rowstart, const int* __restrict__ degv,
    const float* __restrict__ norm, float* __restrict__ out)
{
    const int node = blockIdx.x * 4 + (threadIdx.x >> 6);
    if (node >= N_NODES) return;
    const int lane = threadIdx.x & 63;
    const int grp  = lane >> 4;       // which of 4 concurrent edges
    const int lg   = lane & 15;       // column-quad within the row

    const int beg = rowstart[node];
    const int end = beg + degv[node];

    float4 acc = make_float4(0.f, 0.f, 0.f, 0.f);
    for (int base = beg; base < end; base += 64) {
        int p = base + lane;
        int idx = 0; float w = 0.f;
        if (p < end) { idx = csr_src[p]; w = norm[idx]; }
        const int nb = min(64, end - base);
        const int iters = (nb + 3) >> 2;     // wave-uniform
        for (int i = 0; i < iters; ++i) {
            const int kk = i * 4 + grp;      // <= 63 always
            int s    = __shfl(idx, kk, 64);  // convergent shfl
            float ww = __shfl(w,  kk, 64);
            if (kk < nb) {
                const float4 hv = *(const float4*)(h + (size_t)s * D + lg * 4);
                acc.x = fmaf(hv.x, ww, acc.x);
                acc.y = fmaf(hv.y, ww, acc.y);
                acc.z = fmaf(hv.z, ww, acc.z);
                acc.w = fmaf(hv.w, ww, acc.w);
            }
        }
    }
#pragma unroll
    for (int off = 32; off >= 16; off >>= 1) {
        acc.x += __shfl_down(acc.x, off, 64);
        acc.y += __shfl_down(acc.y, off, 64);
        acc.z += __shfl_down(acc.z, off, 64);
        acc.w += __shfl_down(acc.w, off, 64);
    }
    if (lane < 16) {
        const float nn = norm[node];
        float4 o = make_float4(acc.x * nn, acc.y * nn, acc.z * nn, acc.w * nn);
        *(float4*)(out + (size_t)node * D + (size_t)lane * 4) = o;
    }
}

extern "C" void kernel_launch(void* const* d_in, const int* in_sizes, int n_in,
                              void* d_out, int out_size, void* d_ws, size_t ws_size,
                              hipStream_t stream)
{
    const float* emb  = (const float*)d_in[0];
    const float* gc1w = (const float*)d_in[1];
    const float* gc2w = (const float*)d_in[2];
    const float* gc1h = (const float*)d_in[3];
    const float* gc2h = (const float*)d_in[4];
    const float* w_ih = (const float*)d_in[5];
    const float* w_hh = (const float*)d_in[6];
    const float* b_ih = (const float*)d_in[7];
    const float* b_hh = (const float*)d_in[8];
    const int* src = (const int*)d_in[9];
    const int* dst = (const int*)d_in[10];

    float* ws = (float*)d_ws;
    float* gi1 = ws + OFF_GI1;
    float* gi2 = ws + OFF_GI2;
    float* gh1 = ws + OFF_GH1;
    float* gh2 = ws + OFF_GH2;
    float* w1  = ws + OFF_W1;
    float* w2  = ws + OFF_W2;
    int*   deg = (int*)(ws + OFF_DEG);
    float* nrm = ws + OFF_NORM;
    int*   rows = (int*)(ws + OFF_ROWS);
    int*   bcnt = (int*)(ws + OFF_BCNT);
    int*   bbase = (int*)(ws + OFF_BBASE);
    int*   bcur = (int*)(ws + OFF_BCUR);
    int*   csr  = (int*)(ws + OFF_CSR);
    float* h    = ws + OFF_H;
    int2*  pairs = (int2*)(ws + OFF_H);   // aliases h: dead before transform1
    float* agg1 = ws + OFF_AGG1;
    float* out  = (float*)d_out;

    hipMemsetAsync(deg, 0, NPAD * sizeof(int), stream);
    hipMemsetAsync(bcnt, 0, 256 * sizeof(int), stream);

    // GRU weight evolution: x = hist, hidden = current weights
    gru_matvec<<<D3 / GRU_ROWS, 256, 0, stream>>>(w_ih, w_hh, gc1h, gc2h,
                                                  gc1w, gc2w, gi1, gi2, gh1, gh2);
    gru_gates<<<dim3(16, 2), 256, 0, stream>>>(gi1, gh1, gi2, gh2,
                                               b_ih, b_hh, gc1w, gc2w, w1, w2);

    // degree + buckets + norm + coalesced CSR-by-dst
    deg_hist_kernel<<<512, 256, 0, stream>>>(dst, deg, bcnt);
    bucket_scan_kernel<<<1, 256, 0, stream>>>(bcnt, bbase, bcur);
    norm_kernel<<<(N_NODES + 255) / 256, 256, 0, stream>>>(deg, nrm);
    partition_kernel<<<NBUCK, 256, 0, stream>>>(src, dst, bcur, pairs);
    bucket_csr_kernel<<<NBUCK, 256, 0, stream>>>(pairs, deg, bbase, bcnt, rows, csr);

    // layer 1
    transform_kernel<false><<<(N_NODES + 255) / 256, 256, 0, stream>>>(emb, w1, h);
    aggregate_gather<<<(N_NODES + 3) / 4, 256, 0, stream>>>(h, csr, rows, deg, nrm, agg1);

    // layer 2 (relu applied to layer-1 aggregate inside the transform)
    transform_kernel<true><<<(N_NODES + 255) / 256, 256, 0, stream>>>(agg1, w2, h);
    aggregate_gather<<<(N_NODES + 3) / 4, 256, 0, stream>>>(h, csr, rows, deg, nrm, out);
}

// Round 6
// 693.695 us; speedup vs baseline: 1.1324x; 1.1324x over previous
//
#include <hip/hip_runtime.h>

typedef unsigned int uint_t;

#define N_NODES 100000
#define N_EDGES 1600000
#define D 64
#define D2 4096   // D*D
#define D3 12288  // 3*D2

#define NPAD 100352u  // N_NODES rounded up

#define BSHIFT 9          // 512 nodes per bucket
#define BNODES 512
#define NBUCK 196         // ceil(100000/512)
#define CHUNK 8192        // edges per partition workgroup (196 workgroups)
#define CAP   16384       // LDS staging slots in bucket_csr (mean fill 8192)

#define GRU_ROWS 4        // rows per block in gru_matvec

// ---------- workspace layout (4-byte units) ----------
#define OFF_GI1   0u
#define OFF_GI2   (OFF_GI1 + D3)
#define OFF_GH1   (OFF_GI2 + D3)
#define OFF_GH2   (OFF_GH1 + D3)
#define OFF_W1    (OFF_GH2 + D3)          // 49152
#define OFF_W2    (OFF_W1 + D2)           // 53248
#define OFF_DEG   (OFF_W2 + D2)           // 57344   int[NPAD]
#define OFF_NORM  (OFF_DEG + NPAD)        // 157696  float[NPAD]
#define OFF_ROWS  (OFF_NORM + NPAD)       // 258048  int[NPAD] rowstart (node-ordered)
#define OFF_BCNT  (OFF_ROWS + NPAD)       // 358400  int[256]
#define OFF_BBASE (OFF_BCNT + 256u)       // 358656  int[256]
#define OFF_BCUR  (OFF_BBASE + 256u)      // 358912  int[256]
#define OFF_CSR   (OFF_BCUR + 256u)       // 359168  int[N_EDGES]
#define OFF_H     (OFF_CSR + 1600000u)    // 1959168 slot holds: int2 pairs (12.8MB) then bf16 h' (12.8MB)
#define OFF_AGG1  (OFF_H + 6400000u)      // 8359168 float[N*D]
// total 14,759,168 units ~= 56.3 MiB

__device__ __forceinline__ float dot4(float4 a, float4 b, float acc) {
    acc = fmaf(a.x, b.x, acc);
    acc = fmaf(a.y, b.y, acc);
    acc = fmaf(a.z, b.z, acc);
    acc = fmaf(a.w, b.w, acc);
    return acc;
}

// round-to-nearest-even f32 -> bf16 (value range here is sane, no NaN concern)
__device__ __forceinline__ uint_t bfr(float f) {
    uint_t u = __float_as_uint(f);
    u += 0x7FFFu + ((u >> 16) & 1u);
    return u >> 16;
}

// K1: 4 matvecs in one pass over w_ih,w_hh (fp32).
// R5 post-mortem: 33KB LDS + 6 blocks/CU left occupancy at 19% -> 1.58 TB/s.
// Now: GRU_ROWS=4 (p[] halves -> ~88 VGPR, 4 waves/SIMD bucket), grid 3072
// (12 blocks/CU), and the reduction is per-wave shfl + 256B LDS combine, so
// LDS no longer limits residency. Streaming loop unchanged (8 loads/row in
// flight, x/h fragments in registers).
__global__ __launch_bounds__(256) void gru_matvec(
    const float* __restrict__ w_ih, const float* __restrict__ w_hh,
    const float* __restrict__ x1, const float* __restrict__ x2,
    const float* __restrict__ h1, const float* __restrict__ h2,
    float* __restrict__ gi1, float* __restrict__ gi2,
    float* __restrict__ gh1, float* __restrict__ gh2)
{
    __shared__ float red[4][GRU_ROWS * 4];
    const int tid = threadIdx.x;
    const int r0  = blockIdx.x * GRU_ROWS;

    // thread owns float4 slots {tid, tid+256, tid+512, tid+768}
    float4 fx1[4], fx2[4], fh1[4], fh2[4];
    {
        const float4* vx1 = (const float4*)x1;
        const float4* vx2 = (const float4*)x2;
        const float4* vh1 = (const float4*)h1;
        const float4* vh2 = (const float4*)h2;
#pragma unroll
        for (int c = 0; c < 4; ++c) {
            const int idx = tid + c * 256;
            fx1[c] = vx1[idx]; fx2[c] = vx2[idx];
            fh1[c] = vh1[idx]; fh2[c] = vh2[idx];
        }
    }

    float p[GRU_ROWS][4];
#pragma unroll
    for (int r = 0; r < GRU_ROWS; ++r)
#pragma unroll
        for (int o = 0; o < 4; ++o) p[r][o] = 0.f;

#pragma unroll
    for (int r = 0; r < GRU_ROWS; ++r) {
        const float4* wi = (const float4*)(w_ih + (size_t)(r0 + r) * D2);
        const float4* wh = (const float4*)(w_hh + (size_t)(r0 + r) * D2);
        float4 a[4], b[4];
#pragma unroll
        for (int c = 0; c < 4; ++c) {       // 8 independent streaming loads
            a[c] = wi[tid + c * 256];
            b[c] = wh[tid + c * 256];
        }
#pragma unroll
        for (int c = 0; c < 4; ++c) {
            p[r][0] = dot4(a[c], fx1[c], p[r][0]);
            p[r][1] = dot4(a[c], fx2[c], p[r][1]);
            p[r][2] = dot4(b[c], fh1[c], p[r][2]);
            p[r][3] = dot4(b[c], fh2[c], p[r][3]);
        }
    }

    // per-wave shuffle reduce (convergent), then tiny cross-wave LDS combine
    const int wave = tid >> 6, lane = tid & 63;
#pragma unroll
    for (int k = 0; k < GRU_ROWS * 4; ++k) {
        float v = p[k >> 2][k & 3];
#pragma unroll
        for (int m = 32; m > 0; m >>= 1) v += __shfl_down(v, m, 64);
        if (lane == 0) red[wave][k] = v;
    }
    __syncthreads();
    if (tid < GRU_ROWS * 4) {
        float s = red[0][tid] + red[1][tid] + red[2][tid] + red[3][tid];
        const int row = r0 + (tid >> 2);
        const int o = tid & 3;
        float* outp = (o == 0) ? gi1 : (o == 1) ? gi2 : (o == 2) ? gh1 : gh2;
        outp[row] = s;
    }
}

// K2: GRU gates -> evolved weights w1,w2 (fp32, 4096 each)
__global__ __launch_bounds__(256) void gru_gates(
    const float* __restrict__ gi1, const float* __restrict__ gh1,
    const float* __restrict__ gi2, const float* __restrict__ gh2,
    const float* __restrict__ b_ih, const float* __restrict__ b_hh,
    const float* __restrict__ hw1, const float* __restrict__ hw2,
    float* __restrict__ w1, float* __restrict__ w2)
{
    const int j = blockIdx.x * 256 + threadIdx.x;   // 0..4095
    const int layer = blockIdx.y;
    const float* gi = layer ? gi2 : gi1;
    const float* gh = layer ? gh2 : gh1;
    const float* hw = layer ? hw2 : hw1;
    float* wo = layer ? w2 : w1;

    float ir = gi[j]          + b_ih[j];
    float hr = gh[j]          + b_hh[j];
    float iz = gi[j + D2]     + b_ih[j + D2];
    float hz = gh[j + D2]     + b_hh[j + D2];
    float in_ = gi[j + 2*D2]  + b_ih[j + 2*D2];
    float hn = gh[j + 2*D2]   + b_hh[j + 2*D2];

    float r = 1.f / (1.f + expf(-(ir + hr)));
    float z = 1.f / (1.f + expf(-(iz + hz)));
    float n = tanhf(in_ + r * hn);
    wo[j] = (1.f - z) * n + z * hw[j];
}

// K3: fused in-degree + bucket histogram (grid-stride, LDS-pre-aggregated)
__global__ __launch_bounds__(256) void deg_hist_kernel(
    const int* __restrict__ dst, int* __restrict__ deg, int* __restrict__ bcnt)
{
    __shared__ int hist[256];
    const int tid = threadIdx.x;
    hist[tid] = 0;
    __syncthreads();
    const int stride = gridDim.x * 256;
    for (int e = blockIdx.x * 256 + tid; e < N_EDGES; e += stride) {
        const int d = dst[e];
        atomicAdd(&deg[d], 1);
        atomicAdd(&hist[d >> BSHIFT], 1);
    }
    __syncthreads();
    if (hist[tid]) atomicAdd(&bcnt[tid], hist[tid]);
}

// K4: exclusive scan of 256 bucket counts -> bucket base + write cursor
__global__ __launch_bounds__(256) void bucket_scan_kernel(
    const int* __restrict__ bcnt, int* __restrict__ bbase, int* __restrict__ bcur)
{
    __shared__ int tmp[256];
    const int tid = threadIdx.x;
    const int c = bcnt[tid];
    tmp[tid] = c;
    __syncthreads();
    for (int off = 1; off < 256; off <<= 1) {
        int a = tmp[tid];
        int b = (tid >= off) ? tmp[tid - off] : 0;
        __syncthreads();
        tmp[tid] = a + b;
        __syncthreads();
    }
    const int ex = tmp[tid] - c;
    bbase[tid] = ex;
    bcur[tid]  = ex;
}

// K5: norm = clip(deg,1)^-0.5
__global__ __launch_bounds__(256) void norm_kernel(
    const int* __restrict__ deg, float* __restrict__ norm)
{
    const int n = blockIdx.x * 256 + threadIdx.x;
    if (n < N_NODES) norm[n] = 1.0f / sqrtf(fmaxf((float)deg[n], 1.0f));
}

// K6: partition edges into dst-buckets. All global writes are coalesced runs.
__global__ __launch_bounds__(256) void partition_kernel(
    const int* __restrict__ src, const int* __restrict__ dst,
    int* __restrict__ bcur, int2* __restrict__ pairs)
{
    __shared__ int hist[256];
    __shared__ int lbase[256];
    __shared__ int gbase[256];
    __shared__ int lcur[256];
    __shared__ int2 stage[CHUNK];
    const int tid = threadIdx.x;
    const int e0  = blockIdx.x * CHUNK;
    const int cnt = min(CHUNK, N_EDGES - e0);

    hist[tid] = 0; lcur[tid] = 0;
    __syncthreads();
    for (int i = tid; i < cnt; i += 256)
        atomicAdd(&hist[dst[e0 + i] >> BSHIFT], 1);
    __syncthreads();
    {
        const int c = hist[tid];
        lbase[tid] = c;
        __syncthreads();
        for (int off = 1; off < 256; off <<= 1) {
            int a = lbase[tid];
            int b = (tid >= off) ? lbase[tid - off] : 0;
            __syncthreads();
            lbase[tid] = a + b;
            __syncthreads();
        }
        const int inc = lbase[tid];
        lbase[tid] = inc - c;
        if (c) gbase[tid] = atomicAdd(&bcur[tid], c);
        __syncthreads();
    }
    for (int i = tid; i < cnt; i += 256) {
        const int s = src[e0 + i], d = dst[e0 + i];
        const int b = d >> BSHIFT;
        const int p = lbase[b] + atomicAdd(&lcur[b], 1);
        stage[p] = make_int2(s, d);
    }
    __syncthreads();
    for (int i = tid; i < cnt; i += 256) {
        const int2 v = stage[i];
        const int b = v.y >> BSHIFT;
        pairs[gbase[b] + (i - lbase[b])] = v;
    }
}

// K7: per-bucket CSR finalize (LDS sort, coalesced flush, node-ordered rowstart)
__global__ __launch_bounds__(256) void bucket_csr_kernel(
    const int2* __restrict__ pairs, const int* __restrict__ deg,
    const int* __restrict__ bbase, const int* __restrict__ bcnt,
    int* __restrict__ rowstart, int* __restrict__ csr_src)
{
    __shared__ int lofs[BNODES];
    __shared__ int lcur[BNODES];
    __shared__ int pscan[256];
    __shared__ int stage[CAP];     // 64KB
    const int tid = threadIdx.x;
    const int b   = blockIdx.x;
    const int nodeBase = b << BSHIFT;

    const int n0 = nodeBase + 2 * tid;
    const int d0 = (n0     < N_NODES) ? deg[n0]     : 0;
    const int d1 = (n0 + 1 < N_NODES) ? deg[n0 + 1] : 0;
    pscan[tid] = d0 + d1;
    __syncthreads();
    for (int off = 1; off < 256; off <<= 1) {
        int a = pscan[tid];
        int x = (tid >= off) ? pscan[tid - off] : 0;
        __syncthreads();
        pscan[tid] = a + x;
        __syncthreads();
    }
    const int ex = pscan[tid] - (d0 + d1);
    lofs[2 * tid]     = ex;
    lofs[2 * tid + 1] = ex + d0;
    lcur[2 * tid]     = 0;
    lcur[2 * tid + 1] = 0;

    const int base = bbase[b];
    if (n0     < N_NODES) rowstart[n0]     = base + ex;
    if (n0 + 1 < N_NODES) rowstart[n0 + 1] = base + ex + d0;
    __syncthreads();

    const int cnt = bcnt[b];
    if (cnt <= CAP) {
        for (int i = tid; i < cnt; i += 256) {
            const int2 v = pairs[base + i];
            const int ln = v.y - nodeBase;
            const int p  = lofs[ln] + atomicAdd(&lcur[ln], 1);
            stage[p] = v.x;
        }
        __syncthreads();
        for (int i = tid; i < cnt; i += 256)
            csr_src[base + i] = stage[i];
    } else {
        for (int i = tid; i < cnt; i += 256) {
            const int2 v = pairs[base + i];
            const int ln = v.y - nodeBase;
            const int p  = atomicAdd(&lcur[ln], 1);
            csr_src[base + lofs[ln] + p] = v.x;
        }
    }
}

// K8/K10: dense transform. out_bf16[node] = ((relu?)(x[node]) @ w) * norm[node].
// Pre-scaling by norm[node] folds the per-edge norm[src] gather into the h row
// (aggregate then only needs norm[dst] once). bf16 storage halves the gather
// traffic that dominates aggregate_gather.
template <bool RELU>
__global__ __launch_bounds__(256) void transform_kernel(
    const float* __restrict__ xin, const float* __restrict__ w,
    const float* __restrict__ norm, unsigned short* __restrict__ outbf)
{
    __shared__ float sw[D * D];
    const int tid = threadIdx.x;
#pragma unroll
    for (int i = 0; i < 16; ++i) sw[tid + i * 256] = w[tid + i * 256];
    __syncthreads();

    const int node = blockIdx.x * 256 + tid;
    if (node >= N_NODES) return;

    float x[D];
    const float4* p = (const float4*)(xin + (size_t)node * D);
#pragma unroll
    for (int i = 0; i < 16; ++i) {
        float4 u = p[i];
        x[i * 4 + 0] = u.x; x[i * 4 + 1] = u.y;
        x[i * 4 + 2] = u.z; x[i * 4 + 3] = u.w;
    }
    if (RELU) {
#pragma unroll
        for (int k = 0; k < D; ++k) x[k] = fmaxf(x[k], 0.f);
    }

    float acc[D];
#pragma unroll
    for (int j = 0; j < D; ++j) acc[j] = 0.f;
#pragma unroll
    for (int k = 0; k < D; ++k) {
        float a = x[k];
#pragma unroll
        for (int j = 0; j < D; ++j) acc[j] = fmaf(a, sw[k * D + j], acc[j]);
    }

    const float nn = norm[node];
    uint_t pk[32];
#pragma unroll
    for (int j = 0; j < 32; ++j)
        pk[j] = bfr(acc[2 * j] * nn) | (bfr(acc[2 * j + 1] * nn) << 16);

    uint4* po = (uint4*)(outbf + (size_t)node * D);
#pragma unroll
    for (int i = 0; i < 8; ++i)
        po[i] = make_uint4(pk[4 * i], pk[4 * i + 1], pk[4 * i + 2], pk[4 * i + 3]);
}

// K9/K11: gather aggregation over bf16 h' rows (128B each). One wave per node.
// out[n] = norm[n] * sum_{e in bucket(n)} h'[src_e]   (h' already has norm[src]).
// 16 lanes x 8B (bf16x4) cover a row; 4 edges per step; 8 steps' loads are
// issued back-to-back (8 in flight per wave) before their adds -> latency-bound
// fix (R5: 1 load in flight -> ~32 outstanding lines/CU vs ~55 needed).
// All __shfl are convergent: iters is wave-uniform, kk <= 63 always.
__global__ __launch_bounds__(256) void aggregate_gather(
    const unsigned short* __restrict__ hbf, const int* __restrict__ csr_src,
    const int* __restrict__ rowstart, const int* __restrict__ degv,
    const float* __restrict__ norm, float* __restrict__ out)
{
    const int node = blockIdx.x * 4 + (threadIdx.x >> 6);
    if (node >= N_NODES) return;
    const int lane = threadIdx.x & 63;
    const int grp  = lane >> 4;       // which of 4 concurrent edges
    const int lg   = lane & 15;       // 8B-chunk within the 128B row
    const uint2* hp = (const uint2*)hbf;

    const int beg = rowstart[node];
    const int end = beg + degv[node];

    float4 acc = make_float4(0.f, 0.f, 0.f, 0.f);
    for (int base = beg; base < end; base += 64) {
        int p = base + lane;
        int idx = 0;
        if (p < end) idx = csr_src[p];
        const int nb = min(64, end - base);
        const int iters = (nb + 3) >> 2;     // wave-uniform, <= 16
        for (int i = 0; i < iters; i += 8) {
            uint2 raw[8]; bool act[8];
#pragma unroll
            for (int u = 0; u < 8; ++u) {
                const int kk = (i + u) * 4 + grp;       // <= 63 always
                const int s = __shfl(idx, kk, 64);      // convergent
                act[u] = (kk < nb);
                if (act[u]) raw[u] = hp[(size_t)s * 16 + lg];
            }
#pragma unroll
            for (int u = 0; u < 8; ++u) {
                if (act[u]) {
                    acc.x += __uint_as_float(raw[u].x << 16);
                    acc.y += __uint_as_float(raw[u].x & 0xFFFF0000u);
                    acc.z += __uint_as_float(raw[u].y << 16);
                    acc.w += __uint_as_float(raw[u].y & 0xFFFF0000u);
                }
            }
        }
    }
    // fold the 4 edge-groups: lanes l, l+16, l+32, l+48 hold the same channels
#pragma unroll
    for (int off = 32; off >= 16; off >>= 1) {
        acc.x += __shfl_down(acc.x, off, 64);
        acc.y += __shfl_down(acc.y, off, 64);
        acc.z += __shfl_down(acc.z, off, 64);
        acc.w += __shfl_down(acc.w, off, 64);
    }
    if (lane < 16) {
        const float nn = norm[node];
        float4 o = make_float4(acc.x * nn, acc.y * nn, acc.z * nn, acc.w * nn);
        *(float4*)(out + (size_t)node * D + (size_t)lane * 4) = o;
    }
}

extern "C" void kernel_launch(void* const* d_in, const int* in_sizes, int n_in,
                              void* d_out, int out_size, void* d_ws, size_t ws_size,
                              hipStream_t stream)
{
    const float* emb  = (const float*)d_in[0];
    const float* gc1w = (const float*)d_in[1];
    const float* gc2w = (const float*)d_in[2];
    const float* gc1h = (const float*)d_in[3];
    const float* gc2h = (const float*)d_in[4];
    const float* w_ih = (const float*)d_in[5];
    const float* w_hh = (const float*)d_in[6];
    const float* b_ih = (const float*)d_in[7];
    const float* b_hh = (const float*)d_in[8];
    const int* src = (const int*)d_in[9];
    const int* dst = (const int*)d_in[10];

    float* ws = (float*)d_ws;
    float* gi1 = ws + OFF_GI1;
    float* gi2 = ws + OFF_GI2;
    float* gh1 = ws + OFF_GH1;
    float* gh2 = ws + OFF_GH2;
    float* w1  = ws + OFF_W1;
    float* w2  = ws + OFF_W2;
    int*   deg = (int*)(ws + OFF_DEG);
    float* nrm = ws + OFF_NORM;
    int*   rows = (int*)(ws + OFF_ROWS);
    int*   bcnt = (int*)(ws + OFF_BCNT);
    int*   bbase = (int*)(ws + OFF_BBASE);
    int*   bcur = (int*)(ws + OFF_BCUR);
    int*   csr  = (int*)(ws + OFF_CSR);
    unsigned short* hbf = (unsigned short*)(ws + OFF_H);   // bf16 h' rows
    int2*  pairs = (int2*)(ws + OFF_H + 3200000u);         // disjoint from hbf
    float* agg1 = ws + OFF_AGG1;
    float* out  = (float*)d_out;

    hipMemsetAsync(deg, 0, NPAD * sizeof(int), stream);
    hipMemsetAsync(bcnt, 0, 256 * sizeof(int), stream);

    // GRU weight evolution: x = hist, hidden = current weights
    gru_matvec<<<D3 / GRU_ROWS, 256, 0, stream>>>(w_ih, w_hh, gc1h, gc2h,
                                                  gc1w, gc2w, gi1, gi2, gh1, gh2);
    gru_gates<<<dim3(16, 2), 256, 0, stream>>>(gi1, gh1, gi2, gh2,
                                               b_ih, b_hh, gc1w, gc2w, w1, w2);

    // degree + buckets + norm + coalesced CSR-by-dst
    deg_hist_kernel<<<512, 256, 0, stream>>>(dst, deg, bcnt);
    bucket_scan_kernel<<<1, 256, 0, stream>>>(bcnt, bbase, bcur);
    norm_kernel<<<(N_NODES + 255) / 256, 256, 0, stream>>>(deg, nrm);
    partition_kernel<<<NBUCK, 256, 0, stream>>>(src, dst, bcur, pairs);
    bucket_csr_kernel<<<NBUCK, 256, 0, stream>>>(pairs, deg, bbase, bcnt, rows, csr);

    // layer 1
    transform_kernel<false><<<(N_NODES + 255) / 256, 256, 0, stream>>>(emb, w1, nrm, hbf);
    aggregate_gather<<<(N_NODES + 3) / 4, 256, 0, stream>>>(hbf, csr, rows, deg, nrm, agg1);

    // layer 2 (relu applied to layer-1 aggregate inside the transform)
    transform_kernel<true><<<(N_NODES + 255) / 256, 256, 0, stream>>>(agg1, w2, nrm, hbf);
    aggregate_gather<<<(N_NODES + 3) / 4, 256, 0, stream>>>(hbf, csr, rows, deg, nrm, out);
}